// Round 1
// 4124.853 us; speedup vs baseline: 2.7651x; 2.7651x over previous
//
#include <hip/hip_runtime.h>
#include <stdint.h>

// ---- problem constants ----
#define ENC_HID 768
#define DEC_HID 128
#define EMB_    200
#define VOCAB   32000
#define B_      32
#define S_      256
#define T_      96
#define NSTEP   95          // T-1 decode steps
#define KFC     1096        // 128 + 768 + 200
#define KPAD    1120        // 35 * 32  (K padded for BK=32)
#define MROWS   3040        // 95 * 32
#define MPAD    3072        // 24 * 128
#define NB_N    250         // 32000 / 128
#define NB_M    24          // 3072 / 128

#define NWK 8               // workers (blocks) per batch element
#define SWK 32              // s-values per worker

typedef _Float16 half8 __attribute__((ext_vector_type(8)));
typedef float    floatx4 __attribute__((ext_vector_type(4)));

// ---- workspace layout (bytes), all 16B-aligned ----
#define WS_AHI  ((size_t)0)
#define WS_ALO  (WS_AHI + (size_t)MPAD*KPAD*2)
#define WS_BHI  (WS_ALO + (size_t)MPAD*KPAD*2)
#define WS_BLO  (WS_BHI + (size_t)VOCAB*KPAD*2)
#define WS_PART (WS_BLO + (size_t)VOCAB*KPAD*2)
#define WS_W1T  (WS_PART+ (size_t)NB_N*MPAD*8)
#define WS_W2T  (WS_W1T + (size_t)484*512*8)      // contiguous after W1T: rows 484..547
#define WS_ENCT (WS_W2T + (size_t)64*512*8)
#define WS_GB   (WS_ENCT+ (size_t)32*128*256*4)
#define WS_CH   (WS_GB  + (size_t)512*4)          // commH  [2][32][128] f32
#define WS_CMS  (WS_CH  + (size_t)2*32*128*4)     // commMS [32][8] float2
#define WS_CPW  (WS_CMS + (size_t)32*8*8)         // commPW [32][8][768] f32
#define WS_BAR  (WS_CPW + (size_t)32*8*768*4)     // barcnt [32][32] int (128B-padded lines)
// total ~162.8 MiB

#define SCOPE_AGT __HIP_MEMORY_SCOPE_AGENT

__device__ __forceinline__ float tanh_fast(float x){
  float ax = fabsf(x);
  float t = __builtin_amdgcn_exp2f(-2.8853900817779268f * ax);   // e^{-2|x|}
  float r = (1.0f - t) * __builtin_amdgcn_rcpf(1.0f + t);
  return copysignf(r, x);
}
__device__ __forceinline__ float sigmoid_fast(float x){
  float t = __builtin_amdgcn_exp2f(-1.4426950408889634f * x);
  return __builtin_amdgcn_rcpf(1.0f + t);
}

// ---- agent-scope (coherent-point) data movement: no cache-wide inv needed ----
__device__ __forceinline__ void ast32(float* p, float v){
  __hip_atomic_store(p, v, __ATOMIC_RELAXED, SCOPE_AGT);
}
__device__ __forceinline__ float ald32(const float* p){
  return __hip_atomic_load((float*)p, __ATOMIC_RELAXED, SCOPE_AGT);
}
__device__ __forceinline__ void ast64(void* p, float x, float y){
  union{ float2 f; unsigned long long u; } c; c.f = make_float2(x,y);
  __hip_atomic_store((unsigned long long*)p, c.u, __ATOMIC_RELAXED, SCOPE_AGT);
}
__device__ __forceinline__ float2 ald64(const void* p){
  union{ float2 f; unsigned long long u; } c;
  c.u = __hip_atomic_load((unsigned long long*)p, __ATOMIC_RELAXED, SCOPE_AGT);
  return c.f;
}

// per-batch 8-block barrier: monotonically increasing counter.
// release-RMW arrival (prior sc-flagged stores are drained by the vmcnt(0)
// each wave executes before s_barrier); relaxed spin; data reads after the
// barrier are themselves coherent-point loads, so no acquire-invalidate.
__device__ __forceinline__ void bbar(int* cnt, int target){
  __syncthreads();
  if(threadIdx.x == 0){
    __hip_atomic_fetch_add(cnt, 1, __ATOMIC_RELEASE, SCOPE_AGT);
    while(__hip_atomic_load(cnt, __ATOMIC_RELAXED, SCOPE_AGT) < target)
      __builtin_amdgcn_s_sleep(2);
  }
  __syncthreads();
}

// ============ prep: transpose/pack LSTM weights (fp32 pairs), combine bias ============
__global__ void prep_weights(const float* __restrict__ W_ih,
                             const float* __restrict__ W_hh,
                             const float* __restrict__ b_ih,
                             const float* __restrict__ b_hh,
                             float2* __restrict__ W1T,
                             float2* __restrict__ W2T,
                             float* __restrict__ gbias){
  int i = blockIdx.x*blockDim.x + threadIdx.x;
  const int n1 = 484*512;
  if(i < n1){
    int kk = i >> 9, j = i & 511;
    W1T[i] = make_float2(W_ih[j*968 + 2*kk], W_ih[j*968 + 2*kk+1]);
  } else if(i < n1 + 64*512){
    int r = i - n1; int kk = r >> 9, j = r & 511;
    W2T[r] = make_float2(W_hh[j*128 + 2*kk], W_hh[j*128 + 2*kk+1]);
  } else if(i < n1 + 64*512 + 512){
    int j = i - n1 - 64*512;
    gbias[j] = b_ih[j] + b_hh[j];
  }
}

// ============ prep: encT[b][u][s] = attn_b[u] + enc[b,s,:] @ attn_W[128:,u] ============
__global__ __launch_bounds__(128) void prep_encpart(
    const float* __restrict__ enc,
    const float* __restrict__ attn_W,
    const float* __restrict__ attn_b,
    float* __restrict__ encT){
  int g = blockIdx.x;              // 1024 = 32 b * 32 s-groups
  int b = g >> 5, s0 = (g & 31) << 3;
  int u = threadIdx.x;             // 128
  __shared__ float rowsT[ENC_HID][8];
  for(int r=0;r<8;++r)
    for(int i=u;i<ENC_HID;i+=128)
      rowsT[i][r] = enc[((size_t)(b*S_ + s0 + r))*ENC_HID + i];
  __syncthreads();
  float ab = attn_b[u];
  float acc[8];
  #pragma unroll
  for(int r=0;r<8;++r) acc[r]=ab;
  for(int d=0; d<ENC_HID; ++d){
    float w = attn_W[(128+d)*128 + u];
    #pragma unroll
    for(int r=0;r<8;++r) acc[r] += rowsT[d][r]*w;
  }
  for(int r=0;r<8;++r)
    encT[((size_t)b*128 + u)*256 + (s0+r)] = acc[r];
}

// ============ prep: fc_W (fp32) -> f16 hi/lo split, B scaled x64, lo x2048 ============
__global__ void prep_B(const float* __restrict__ fcW,
                       _Float16* __restrict__ Bhi, _Float16* __restrict__ Blo){
  size_t i = (size_t)blockIdx.x*blockDim.x + threadIdx.x;   // 32000*1120 exact
  size_t row = i / KPAD; int col = (int)(i - row*KPAD);
  float x = 0.f;
  if(col < KFC) x = fcW[row*KFC + col] * 64.0f;
  _Float16 hi = (_Float16)x;
  Bhi[i] = hi;
  Blo[i] = (_Float16)((x - (float)hi) * 2048.0f);
}

// ============ zero t=0 logits slice + t=0 tokens + comm state ============
#define ZN (B_*VOCAB + B_ + 2*32*128 + 32*32)
__global__ void zero_t0(float* __restrict__ out,
                        float* __restrict__ commH,
                        int* __restrict__ barcnt){
  int i = blockIdx.x*blockDim.x + threadIdx.x;
  if(i < B_*VOCAB){
    int b = i / VOCAB, v = i - (i/VOCAB)*VOCAB;
    out[(size_t)b*T_*VOCAB + v] = 0.f;
  } else if(i < B_*VOCAB + B_){
    int b = i - B_*VOCAB;
    out[(size_t)B_*T_*VOCAB + (size_t)b*T_] = 0.f;
  } else if(i < B_*VOCAB + B_ + 2*32*128){
    commH[i - B_*VOCAB - B_] = 0.f;
  } else if(i < ZN){
    barcnt[i - B_*VOCAB - B_ - 2*32*128] = 0;
  }
}

// ============ recurrence: 8 cooperating blocks per batch, enc LDS-resident ============
// block blk = b*8 + w : batch b, worker w owns s in [32w,32w+32) and h-rows [16w,16w+16)
__global__ __launch_bounds__(512) void recurrence_mw(
    const float*  __restrict__ enc,        // [32,256,768]
    const int*    __restrict__ trg,        // [32,96]
    const float*  __restrict__ embedding,  // [32000,200]
    const float*  __restrict__ attn_W,     // [896,128]
    const float*  __restrict__ attn_v,     // [128]
    const float2* __restrict__ WT,         // [548][512] k-pairs: W1T(484) ++ W2T(64)
    const float*  __restrict__ gbias,      // [512]
    const float*  __restrict__ encT,       // [32,128,256]
    _Float16* __restrict__ Ahi, _Float16* __restrict__ Alo,
    float*  __restrict__ commH,            // [2][32][128]
    float2* __restrict__ commMS,           // [32][8] (m_w, S_w)
    float*  __restrict__ commPW,           // [32][8][768]
    int*    __restrict__ barcnt){          // [32][32]
  const float LOG2E = 1.4426950408889634f;
  int blk = blockIdx.x;
  int b = blk >> 3, w = blk & 7;
  int tid = threadIdx.x;
  int s0 = w * SWK;

  __shared__ float encs[SWK][ENC_HID];     // 96 KB, resident all 95 steps
  __shared__ float encTs[128][SWK+1];      // 16.5 KB
  __shared__ float hl[128], hp_[128], emb[200], av[SWK], wv_[768], vls[128];
  __shared__ float red1[4][128];
  __shared__ float red2[8][SWK];
  __shared__ float red7[64][9];
  __shared__ float2 xv[548];
  __shared__ float xg[64], cl[16], hsl[16];
  __shared__ float msh[8][2];

  // one-time staging
  {
    const float4* eg = (const float4*)(enc + ((size_t)b*S_ + s0)*ENC_HID);
    float4* es4 = (float4*)&encs[0][0];
    for(int i=tid; i<SWK*ENC_HID/4; i+=512) es4[i] = eg[i];
    for(int i=tid; i<128*SWK; i+=512){
      int u = i>>5, s = i&31;
      encTs[u][s] = encT[((size_t)b*128 + u)*256 + s0 + s];
    }
    if(tid<128) vls[tid] = attn_v[tid];
    if(tid<16)  cl[tid]  = 0.f;
  }
  int* cnt = barcnt + b*32;
  int tgt = 0;
  __syncthreads();

  for(int t=0; t<NSTEP; ++t){
    // ---- P0: fetch h (coherent) + emb ----
    int tok = trg[b*T_ + t];
    if(tid<128)
      hl[tid] = ald32(&commH[(((t&1)*B_) + b)*128 + tid]);
    if(tid>=256 && tid<456)
      emb[tid-256] = embedding[(size_t)tok*EMB_ + (tid-256)];
    __syncthreads();

    // ---- P1: hp[u] = sum_k h[k]*attn_W[k][u]  (redundant per worker, L2-hot) ----
    {
      int u = tid & 127, q = tid >> 7;          // 4 k-quarters of 32
      const float* wp = attn_W + (size_t)(q*32)*128 + u;
      float acc = 0.f;
      #pragma unroll 8
      for(int k=0;k<32;++k) acc += hl[q*32+k]*wp[(size_t)k*128];
      red1[q][u] = acc;
    }
    __syncthreads();
    if(tid<128) hp_[tid] = red1[0][tid]+red1[1][tid]+red1[2][tid]+red1[3][tid];
    __syncthreads();

    // ---- P2: energies for own 32 s (LDS-resident encT slice) ----
    if(tid<256){
      int s = tid&31, ug = tid>>5;              // 8 u-groups of 16
      float acc = 0.f;
      #pragma unroll
      for(int i=0;i<16;++i){
        int u = ug*16 + i;
        acc += vls[u]*tanh_fast(encTs[u][s] + hp_[u]);
      }
      red2[ug][s] = acc;
    }
    __syncthreads();

    // ---- P3: local softmax (max + exp-sum relative to local max) ----
    if(tid<32){
      float e = red2[0][tid]+red2[1][tid]+red2[2][tid]+red2[3][tid]
              + red2[4][tid]+red2[5][tid]+red2[6][tid]+red2[7][tid];
      float m = e;
      #pragma unroll
      for(int off=16; off; off>>=1) m = fmaxf(m, __shfl_xor(m, off));
      float p = __builtin_amdgcn_exp2f((e-m)*LOG2E);
      av[tid] = p;
      float ss = p;
      #pragma unroll
      for(int off=16; off; off>>=1) ss += __shfl_xor(ss, off);
      if(tid==0) ast64(&commMS[b*8 + w], m, ss);
    }
    __syncthreads();

    // ---- P4: partial weighted sum from LDS enc slice ----
    if(tid<384){
      float a0=0.f, a1=0.f;
      #pragma unroll 4
      for(int s=0;s<SWK;++s){
        float as = av[s];
        a0 += as*encs[s][2*tid];
        a1 += as*encs[s][2*tid+1];
      }
      ast64(&commPW[((size_t)(b*8+w))*768 + 2*tid], a0, a1);
    }

    // ---- BARRIER A: softmax partials + pw published ----
    tgt += 8; bbar(cnt, tgt);

    // ---- P6: reconstruct full weighted vector ----
    if(tid<8){
      float2 ms = ald64(&commMS[b*8 + tid]);
      msh[tid][0]=ms.x; msh[tid][1]=ms.y;
    }
    __syncthreads();
    {
      float M = msh[0][0];
      #pragma unroll
      for(int i=1;i<8;++i) M = fmaxf(M, msh[i][0]);
      float e2[8]; float Z = 0.f;
      #pragma unroll
      for(int i=0;i<8;++i){
        e2[i] = __builtin_amdgcn_exp2f((msh[i][0]-M)*LOG2E);
        Z += msh[i][1]*e2[i];
      }
      float rZ = 1.0f/Z;
      if(tid<384){
        float a0=0.f, a1=0.f;
        #pragma unroll
        for(int i=0;i<8;++i){
          float2 pv = ald64(&commPW[((size_t)(b*8+i))*768 + 2*tid]);
          float sc = e2[i]*rZ;
          a0 += pv.x*sc; a1 += pv.y*sc;
        }
        wv_[2*tid]=a0; wv_[2*tid+1]=a1;
      }
    }
    __syncthreads();

    // ---- P7a: build x-pair vector [emb | weighted | h] ----
    for(int i=tid; i<548; i+=512){
      float x0,x1; int k2 = 2*i;
      if(i<100){ x0=emb[k2]; x1=emb[k2+1]; }
      else if(i<484){ x0=wv_[k2-200]; x1=wv_[k2-199]; }
      else { x0=hl[k2-968]; x1=hl[k2-967]; }
      xv[i] = make_float2(x0,x1);
    }
    __syncthreads();

    // ---- P7b: 64-gate j-slice, 8-way k-split (worker's W-slice stays L2-hot) ----
    {
      int jl = tid & 63, ks = tid >> 6;
      int j = w*16 + (jl&15) + ((jl>>4)<<7);
      int k0 = ks*68 + (ks<4?ks:4);
      int k1 = k0 + 68 + (ks<4?1:0);
      const float2* wp = WT + (size_t)k0*512 + j;
      float acc = 0.f;
      #pragma unroll 4
      for(int kk=k0; kk<k1; ++kk){
        float2 wv2 = *wp; wp += 512;
        float2 x = xv[kk];
        acc += wv2.x*x.x + wv2.y*x.y;
      }
      red7[jl][ks] = acc;
    }
    __syncthreads();
    if(tid<64){
      int j = w*16 + (tid&15) + ((tid>>4)<<7);
      float g = gbias[j];
      #pragma unroll
      for(int k=0;k<8;++k) g += red7[tid][k];
      xg[tid] = g;
    }
    __syncthreads();

    // ---- P8: LSTM cell for own 16 h-rows; publish h-slice ----
    if(tid<16){
      float gi=xg[tid], gf=xg[16+tid], gg=xg[32+tid], go=xg[48+tid];
      float cn = sigmoid_fast(gf)*cl[tid] + sigmoid_fast(gi)*tanh_fast(gg);
      float hn = sigmoid_fast(go)*tanh_fast(cn);
      cl[tid]=cn; hsl[tid]=hn;
      ast32(&commH[((((t+1)&1))*B_ + b)*128 + w*16 + tid], hn);
    }

    // ---- P9: emit this worker's share of the fc-input row (f16 hi/lo) ----
    {
      size_t base = ((size_t)t*32 + b)*KPAD;
      float v = 0.f; int col = -1;
      if(tid<16){ col = w*16 + tid; v = hsl[tid]; }
      else if(tid<112){ int i=tid-16;  col = 128 + 96*w + i; v = wv_[96*w+i]; }
      else if(tid<137){ int i=tid-112; col = 896 + 25*w + i; v = emb[25*w+i]; }
      else if(w==7 && tid<161){ col = 1096 + (tid-137); v = 0.f; }
      if(col>=0){
        _Float16 hi = (_Float16)v;
        Ahi[base+col] = hi;
        Alo[base+col] = (_Float16)((v-(float)hi)*2048.0f);
      }
    }

    // ---- BARRIER B: h published for next step ----
    tgt += 8; bbar(cnt, tgt);
  }
}

// ============ split-f16 MFMA GEMM: C = (Ahi+Alo/2048) . (Bhi+Blo/2048)^T / 64 ============
__global__ __launch_bounds__(256) void gemm_fc(
    const _Float16* __restrict__ Ahi, const _Float16* __restrict__ Alo,
    const _Float16* __restrict__ Bhi, const _Float16* __restrict__ Blo,
    const float* __restrict__ fcb,
    float* __restrict__ out, unsigned long long* __restrict__ part){
  int blk = blockIdx.x;
  int mb = blk % NB_M, nb = blk / NB_M;
  int m0 = mb*128, n0 = nb*128;
  int tid = threadIdx.x;
  int lane = tid & 63, wv = tid >> 6;
  int wm = (wv & 1)*64, wn = (wv >> 1)*64;
  int l15 = lane & 15, q = lane >> 4;
  __shared__ _Float16 Ahs[128*40];
  __shared__ _Float16 Als[128*40];
  __shared__ _Float16 Bhs[128*40];
  __shared__ _Float16 Bls[128*40];
  __shared__ unsigned long long pl[128*2];
  floatx4 acc1[4][4] = {};
  floatx4 acc2[4][4] = {};
  for(int p=0;p<35;++p){
    __syncthreads();
    #pragma unroll
    for(int i=0;i<2;++i){
      int ch = tid + i*256;
      int row = ch >> 2, kc = ch & 3;
      uint4 va = *((const uint4*)(Ahi + (size_t)(m0+row)*KPAD + p*32) + kc);
      uint4 vb = *((const uint4*)(Alo + (size_t)(m0+row)*KPAD + p*32) + kc);
      uint4 vc = *((const uint4*)(Bhi + (size_t)(n0+row)*KPAD + p*32) + kc);
      uint4 vd = *((const uint4*)(Blo + (size_t)(n0+row)*KPAD + p*32) + kc);
      *(uint4*)&Ahs[row*40 + kc*8] = va;
      *(uint4*)&Als[row*40 + kc*8] = vb;
      *(uint4*)&Bhs[row*40 + kc*8] = vc;
      *(uint4*)&Bls[row*40 + kc*8] = vd;
    }
    __syncthreads();
    half8 bh[4], bl[4];
    #pragma unroll
    for(int ni=0;ni<4;++ni){
      bh[ni] = *(half8*)&Bhs[(wn+ni*16+l15)*40 + q*8];
      bl[ni] = *(half8*)&Bls[(wn+ni*16+l15)*40 + q*8];
    }
    #pragma unroll
    for(int mi=0;mi<4;++mi){
      half8 ah = *(half8*)&Ahs[(wm+mi*16+l15)*40 + q*8];
      half8 al = *(half8*)&Als[(wm+mi*16+l15)*40 + q*8];
      #pragma unroll
      for(int ni=0;ni<4;++ni){
        acc1[mi][ni] = __builtin_amdgcn_mfma_f32_16x16x32_f16(ah, bh[ni], acc1[mi][ni],0,0,0);
        acc2[mi][ni] = __builtin_amdgcn_mfma_f32_16x16x32_f16(ah, bl[ni], acc2[mi][ni],0,0,0);
        acc2[mi][ni] = __builtin_amdgcn_mfma_f32_16x16x32_f16(al, bh[ni], acc2[mi][ni],0,0,0);
      }
    }
  }
  const float S1 = 1.0f/64.0f;
  const float S2 = 1.0f/(64.0f*2048.0f);
  float fcbv[4];
  #pragma unroll
  for(int ni=0;ni<4;++ni) fcbv[ni] = fcb[n0+wn+ni*16+l15];
  #pragma unroll
  for(int mi=0;mi<4;++mi){
    #pragma unroll
    for(int r=0;r<4;++r){
      int gm = m0 + wm + mi*16 + q*4 + r;
      bool valid = gm < MROWS;
      int tt = gm >> 5, bb = gm & 31;
      size_t obase = (size_t)bb*T_*VOCAB + (size_t)(tt+1)*VOCAB;
      float bestv = -3.4e38f; int bestc = 0;
      #pragma unroll
      for(int ni=0;ni<4;++ni){
        int gn = n0 + wn + ni*16 + l15;
        float val = acc1[mi][ni][r]*S1 + acc2[mi][ni][r]*S2 + fcbv[ni];
        if(valid) out[obase + gn] = val;
        if(val > bestv){ bestv = val; bestc = gn; }
      }
      unsigned int ku = __float_as_uint(bestv);
      ku = (ku & 0x80000000u) ? ~ku : (ku | 0x80000000u);
      unsigned long long key = ((unsigned long long)ku<<32)
                             | (unsigned long long)(0xFFFFFFFFu - (unsigned int)bestc);
      #pragma unroll
      for(int off=1; off<16; off<<=1){
        unsigned long long o = __shfl_xor(key, off);
        key = (o > key) ? o : key;
      }
      if(l15==0){
        int row_local = wm + mi*16 + q*4 + r;
        pl[row_local*2 + (wv>>1)] = key;
      }
    }
  }
  __syncthreads();
  if(tid < 128){
    unsigned long long k0 = pl[tid*2], k1 = pl[tid*2+1];
    unsigned long long k = k0>k1?k0:k1;
    int gm = m0 + tid;
    if(gm < MROWS) part[(size_t)nb*MPAD + gm] = k;
  }
}

// ============ final argmax over 250 column-block partials ============
__global__ void argmax_final(const unsigned long long* __restrict__ part,
                             float* __restrict__ out){
  int m = blockIdx.x;
  int lane = threadIdx.x;
  unsigned long long k = 0;
  for(int nb=lane; nb<NB_N; nb+=64){
    unsigned long long v = part[(size_t)nb*MPAD + m];
    if(v>k) k=v;
  }
  for(int off=32;off;off>>=1){
    unsigned long long o = __shfl_xor(k, off);
    if(o>k) k=o;
  }
  if(lane==0){
    unsigned int col = 0xFFFFFFFFu - (unsigned int)(k & 0xFFFFFFFFull);
    int tt = m >> 5, bb = m & 31;
    out[(size_t)B_*T_*VOCAB + (size_t)bb*T_ + (tt+1)] = (float)col;
  }
}

extern "C" void kernel_launch(void* const* d_in, const int* in_sizes, int n_in,
                              void* d_out, int out_size, void* d_ws, size_t ws_size,
                              hipStream_t stream){
  const float* enc       = (const float*)d_in[0];
  const int*   trg       = (const int*)d_in[1];
  const float* embedding = (const float*)d_in[2];
  const float* attn_W    = (const float*)d_in[3];
  const float* attn_b    = (const float*)d_in[4];
  const float* attn_v    = (const float*)d_in[5];
  const float* W_ih      = (const float*)d_in[6];
  const float* W_hh      = (const float*)d_in[7];
  const float* b_ih      = (const float*)d_in[8];
  const float* b_hh      = (const float*)d_in[9];
  const float* fcW       = (const float*)d_in[10];
  const float* fcb       = (const float*)d_in[11];
  float* out = (float*)d_out;
  char* ws = (char*)d_ws;
  _Float16* Ahi = (_Float16*)(ws + WS_AHI);
  _Float16* Alo = (_Float16*)(ws + WS_ALO);
  _Float16* Bhi = (_Float16*)(ws + WS_BHI);
  _Float16* Blo = (_Float16*)(ws + WS_BLO);
  unsigned long long* part = (unsigned long long*)(ws + WS_PART);
  float2* W1T = (float2*)(ws + WS_W1T);
  float2* W2T = (float2*)(ws + WS_W2T);     // contiguous after W1T: WT rows 484..547
  float* encT  = (float*)(ws + WS_ENCT);
  float* gbias = (float*)(ws + WS_GB);
  float* commH  = (float*)(ws + WS_CH);
  float2* commMS = (float2*)(ws + WS_CMS);
  float* commPW = (float*)(ws + WS_CPW);
  int* barcnt   = (int*)(ws + WS_BAR);

  prep_weights<<<(281088+255)/256, 256, 0, stream>>>(W_ih, W_hh, b_ih, b_hh, W1T, W2T, gbias);
  prep_encpart<<<1024, 128, 0, stream>>>(enc, attn_W, attn_b, encT);
  prep_B<<<140000, 256, 0, stream>>>(fcW, Bhi, Blo);
  zero_t0<<<(ZN + 255)/256, 256, 0, stream>>>(out, commH, barcnt);

  {
    void* ka[] = {(void*)&enc,(void*)&trg,(void*)&embedding,(void*)&attn_W,(void*)&attn_v,
                  (void*)&W1T,(void*)&gbias,(void*)&encT,(void*)&Ahi,(void*)&Alo,
                  (void*)&commH,(void*)&commMS,(void*)&commPW,(void*)&barcnt};
    hipError_t e = hipLaunchCooperativeKernel((const void*)recurrence_mw,
                                              dim3(256), dim3(512), ka, 0, stream);
    if(e != hipSuccess){
      // fallback: 1 block/CU (131KB LDS) on a 256-CU chip is fully resident
      recurrence_mw<<<256, 512, 0, stream>>>(enc, trg, embedding, attn_W, attn_v,
                                             W1T, gbias, encT, Ahi, Alo,
                                             commH, commMS, commPW, barcnt);
    }
  }

  gemm_fc<<<NB_M*NB_N, 256, 0, stream>>>(Ahi, Alo, Bhi, Blo, fcb, out, part);
  argmax_final<<<MROWS, 64, 0, stream>>>(part, out);
}